// Round 1
// baseline (998.790 us; speedup 1.0000x reference)
//
#include <hip/hip_runtime.h>
#include <cstddef>

#define NN 100000
#define NE 1600000

// ---------------- degree count ----------------
__global__ void __launch_bounds__(256) k_count(const int* __restrict__ dst,
                                               unsigned* __restrict__ cnt, int E) {
  int i = blockIdx.x * 256 + threadIdx.x;
  if (i < E) atomicAdd(&cnt[dst[i]], 1u);
}

__global__ void __launch_bounds__(256) k_dis(const unsigned* __restrict__ cnt,
                                             float* __restrict__ dis, int N) {
  int i = blockIdx.x * 256 + threadIdx.x;
  if (i < N) dis[i] = rsqrtf((float)cnt[i] + 1.0f);
}

// ---------------- single-block exclusive scan (CSR row_ptr) ----------------
__global__ void __launch_bounds__(1024) k_scan(const unsigned* __restrict__ cnt,
                                               int* __restrict__ row_ptr,
                                               int* __restrict__ cursor, int N) {
  __shared__ unsigned wsum[16];
  __shared__ unsigned s_off, s_tot;
  int tid = threadIdx.x, lane = tid & 63, wv = tid >> 6;
  if (tid == 0) s_off = 0u;
  __syncthreads();
  for (int base = 0; base < N; base += 1024) {
    int i = base + tid;
    unsigned v = (i < N) ? cnt[i] : 0u;
    unsigned x = v;
    #pragma unroll
    for (int d = 1; d < 64; d <<= 1) {
      unsigned y = __shfl_up(x, (unsigned)d, 64);
      if (lane >= d) x += y;
    }
    if (lane == 63) wsum[wv] = x;          // inclusive wave total
    __syncthreads();                       // A
    if (tid == 0) {                        // serial scan of 16 wave totals
      unsigned run = 0;
      #pragma unroll
      for (int j = 0; j < 16; ++j) { unsigned t = wsum[j]; wsum[j] = run; run += t; }
      s_tot = run;
    }
    __syncthreads();                       // B
    unsigned excl = s_off + wsum[wv] + (x - v);
    if (i < N) { row_ptr[i] = (int)excl; cursor[i] = (int)excl; }
    unsigned tot = s_tot;
    __syncthreads();                       // C (everyone done reading s_off/wsum)
    if (tid == 0) s_off += tot;            // ordered before next iter's reads by barrier A
  }
  if (tid == 0) row_ptr[N] = (int)s_off;   // == E
}

// ---------------- scatter edges into CSR order ----------------
__global__ void __launch_bounds__(256) k_scatter(const int* __restrict__ src,
                                                 const int* __restrict__ dst,
                                                 const float* __restrict__ dis,
                                                 int* __restrict__ cursor,
                                                 int* __restrict__ src_sorted,
                                                 float* __restrict__ coef, int E) {
  int i = blockIdx.x * 256 + threadIdx.x;
  if (i < E) {
    int s = src[i], d = dst[i];
    int pos = atomicAdd(&cursor[d], 1);
    src_sorted[pos] = s;
    coef[pos] = dis[s] * dis[d];
  }
}

// ---------------- GEMM: H[M][FOUT] = X[M][128] @ W[128][FOUT] ----------------
// 64-row tile per 256-thread block, K chunked by 32, X tile transposed in LDS.
template <int FOUT>
__global__ void __launch_bounds__(256) k_gemm(const float* __restrict__ X,
                                              const float* __restrict__ W,
                                              float* __restrict__ H, int M) {
  constexpr int CPT = FOUT / 16;           // cols per thread (8 or 4)
  constexpr int F4 = FOUT / 4;
  __shared__ float Xs[32][72];             // [k][m], padded stride
  __shared__ float Ws[32][FOUT];
  int tid = threadIdx.x;
  int tx = tid & 15, ty = tid >> 4;        // tx: col group, ty: row group
  int m0 = blockIdx.x * 64;

  float acc[4][CPT];
  #pragma unroll
  for (int i = 0; i < 4; ++i)
    #pragma unroll
    for (int j = 0; j < CPT; ++j) acc[i][j] = 0.f;

  for (int k0 = 0; k0 < 128; k0 += 32) {
    // load X tile (64 rows x 32 k), transposed into Xs[k][m]
    #pragma unroll
    for (int idx = tid; idx < 512; idx += 256) {
      int r = idx >> 3, c4 = idx & 7;
      int g = m0 + r;
      float4 v = make_float4(0.f, 0.f, 0.f, 0.f);
      if (g < M) v = *reinterpret_cast<const float4*>(X + (size_t)g * 128 + k0 + c4 * 4);
      Xs[c4 * 4 + 0][r] = v.x;
      Xs[c4 * 4 + 1][r] = v.y;
      Xs[c4 * 4 + 2][r] = v.z;
      Xs[c4 * 4 + 3][r] = v.w;
    }
    // load W tile (32 k x FOUT)
    for (int idx = tid; idx < 32 * (F4); idx += 256) {
      int kk = idx / F4, c4 = idx % F4;
      float4 v = *reinterpret_cast<const float4*>(W + (size_t)(k0 + kk) * FOUT + c4 * 4);
      *reinterpret_cast<float4*>(&Ws[kk][c4 * 4]) = v;
    }
    __syncthreads();

    #pragma unroll
    for (int kk = 0; kk < 32; ++kk) {
      float4 xv = *reinterpret_cast<const float4*>(&Xs[kk][ty * 4]);
      float xa[4] = {xv.x, xv.y, xv.z, xv.w};
      float wl[CPT];
      float4 w0 = *reinterpret_cast<const float4*>(&Ws[kk][tx * CPT]);
      wl[0] = w0.x; wl[1] = w0.y; wl[2] = w0.z; wl[3] = w0.w;
      if (CPT == 8) {
        float4 w1 = *reinterpret_cast<const float4*>(&Ws[kk][tx * CPT + 4]);
        wl[4] = w1.x; wl[5] = w1.y; wl[6] = w1.z; wl[7] = w1.w;
      }
      #pragma unroll
      for (int i = 0; i < 4; ++i)
        #pragma unroll
        for (int j = 0; j < CPT; ++j)
          acc[i][j] = fmaf(xa[i], wl[j], acc[i][j]);
    }
    __syncthreads();
  }

  #pragma unroll
  for (int i = 0; i < 4; ++i) {
    int g = m0 + ty * 4 + i;
    if (g < M) {
      float4 o0 = make_float4(acc[i][0], acc[i][1], acc[i][2], acc[i][3]);
      *reinterpret_cast<float4*>(H + (size_t)g * FOUT + tx * CPT) = o0;
      if (CPT == 8) {
        float4 o1 = make_float4(acc[i][4], acc[i][5], acc[i][6], acc[i][7]);
        *reinterpret_cast<float4*>(H + (size_t)g * FOUT + tx * CPT + 4) = o1;
      }
    }
  }
}

// ---------------- aggregate: out[n] = sum_{e: dst=n} coef*h[src] + dis[n]^2*h[n] + b ----------------
// one wave per node
template <int F, bool RELU>
__global__ void __launch_bounds__(256) k_agg(const float* __restrict__ h,
                                             const int* __restrict__ row_ptr,
                                             const int* __restrict__ src_sorted,
                                             const float* __restrict__ coef,
                                             const float* __restrict__ dis,
                                             const float* __restrict__ bias,
                                             float* __restrict__ out, int N) {
  int n = blockIdx.x * 4 + (threadIdx.x >> 6);
  int lane = threadIdx.x & 63;
  if (n >= N) return;
  int beg = row_ptr[n], end = row_ptr[n + 1];
  if (F == 128) {
    const float2* __restrict__ h2 = reinterpret_cast<const float2*>(h);
    float2 acc = make_float2(0.f, 0.f);
    for (int p = beg; p < end; ++p) {
      int s = src_sorted[p];
      float c = coef[p];
      float2 v = h2[(size_t)s * 64 + lane];
      acc.x += v.x * c;
      acc.y += v.y * c;
    }
    float dn = dis[n];
    float sc = dn * dn;
    float2 hv = h2[(size_t)n * 64 + lane];
    float2 b = reinterpret_cast<const float2*>(bias)[lane];
    acc.x += sc * hv.x + b.x;
    acc.y += sc * hv.y + b.y;
    if (RELU) { acc.x = fmaxf(acc.x, 0.f); acc.y = fmaxf(acc.y, 0.f); }
    reinterpret_cast<float2*>(out)[(size_t)n * 64 + lane] = acc;
  } else {
    float acc = 0.f;
    for (int p = beg; p < end; ++p)
      acc += h[(size_t)src_sorted[p] * F + lane] * coef[p];
    float dn = dis[n];
    acc += dn * dn * h[(size_t)n * F + lane] + bias[lane];
    if (RELU) acc = fmaxf(acc, 0.f);
    out[(size_t)n * F + lane] = acc;
  }
}

// ---------------- log_softmax over 64 cols, one wave per node ----------------
__global__ void __launch_bounds__(256) k_lsm(const float* __restrict__ in,
                                             float* __restrict__ out, int N) {
  int n = blockIdx.x * 4 + (threadIdx.x >> 6);
  int lane = threadIdx.x & 63;
  if (n >= N) return;
  float v = in[(size_t)n * 64 + lane];
  float m = v;
  #pragma unroll
  for (int d = 32; d; d >>= 1) m = fmaxf(m, __shfl_xor(m, d, 64));
  float e = expf(v - m);
  #pragma unroll
  for (int d = 32; d; d >>= 1) e += __shfl_xor(e, d, 64);
  float s = e;  // wave-total after butterfly (all lanes hold sum)
  out[(size_t)n * 64 + lane] = v - m - logf(s);
}

extern "C" void kernel_launch(void* const* d_in, const int* in_sizes, int n_in,
                              void* d_out, int out_size, void* d_ws, size_t ws_size,
                              hipStream_t stream) {
  const float* x  = (const float*)d_in[0];
  const int*   ei = (const int*)d_in[1];
  const float* W0 = (const float*)d_in[2];
  const float* b0 = (const float*)d_in[3];
  const float* W1 = (const float*)d_in[4];
  const float* b1 = (const float*)d_in[5];
  const float* W2 = (const float*)d_in[6];
  const float* b2 = (const float*)d_in[7];
  float* out = (float*)d_out;

  const int N = NN, E = NE;
  const int* src = ei;
  const int* dst = ei + E;

  char* ws = (char*)d_ws;
  size_t off = 0;
  auto alloc = [&](size_t bytes) -> void* {
    off = (off + 255) & ~(size_t)255;
    void* p = ws + off;
    off += bytes;
    return p;
  };
  float*    dis        = (float*)alloc((size_t)N * 4);
  unsigned* cnt        = (unsigned*)alloc((size_t)N * 4);
  int*      row_ptr    = (int*)alloc((size_t)(N + 1) * 4);
  int*      cursor     = (int*)alloc((size_t)N * 4);
  int*      src_sorted = (int*)alloc((size_t)E * 4);
  float*    coef       = (float*)alloc((size_t)E * 4);
  float*    bufA       = (float*)alloc((size_t)N * 128 * 4);
  float*    bufB       = (float*)alloc((size_t)N * 128 * 4);

  // ---- CSR build (per call; reused across all 3 layers) ----
  hipMemsetAsync(cnt, 0, (size_t)N * 4, stream);
  k_count<<<(E + 255) / 256, 256, 0, stream>>>(dst, cnt, E);
  k_dis<<<(N + 255) / 256, 256, 0, stream>>>(cnt, dis, N);
  k_scan<<<1, 1024, 0, stream>>>(cnt, row_ptr, cursor, N);
  k_scatter<<<(E + 255) / 256, 256, 0, stream>>>(src, dst, dis, cursor, src_sorted, coef, E);

  const int gemm_grid = (N + 63) / 64;   // 1563
  const int node_grid = (N + 3) / 4;     // 25000

  // ---- layer 0 ----
  k_gemm<128><<<gemm_grid, 256, 0, stream>>>(x, W0, bufA, N);
  k_agg<128, true><<<node_grid, 256, 0, stream>>>(bufA, row_ptr, src_sorted, coef, dis, b0, bufB, N);
  // ---- layer 1 ----
  k_gemm<128><<<gemm_grid, 256, 0, stream>>>(bufB, W1, bufA, N);
  k_agg<128, true><<<node_grid, 256, 0, stream>>>(bufA, row_ptr, src_sorted, coef, dis, b1, bufB, N);
  // ---- layer 2 ----
  k_gemm<64><<<gemm_grid, 256, 0, stream>>>(bufB, W2, bufA, N);
  k_agg<64, false><<<node_grid, 256, 0, stream>>>(bufA, row_ptr, src_sorted, coef, dis, b2, bufB, N);
  // ---- log_softmax ----
  k_lsm<<<node_grid, 256, 0, stream>>>(bufB, out, N);
}

// Round 2
// 710.031 us; speedup vs baseline: 1.4067x; 1.4067x over previous
//
#include <hip/hip_runtime.h>
#include <cstddef>

#define NN 100000
#define NE 1600000

// ---------------- degree count ----------------
__global__ void __launch_bounds__(256) k_count(const int* __restrict__ dst,
                                               unsigned* __restrict__ cnt, int E) {
  int i = blockIdx.x * 256 + threadIdx.x;
  if (i < E) atomicAdd(&cnt[dst[i]], 1u);
}

__global__ void __launch_bounds__(256) k_dis(const unsigned* __restrict__ cnt,
                                             float* __restrict__ dis, int N) {
  int i = blockIdx.x * 256 + threadIdx.x;
  if (i < N) dis[i] = rsqrtf((float)cnt[i] + 1.0f);
}

// ---------------- 3-pass scan (replaces serial single-block scan) ----------------
// pass 1: per-1024-block sums
__global__ void __launch_bounds__(1024) k_scan1(const unsigned* __restrict__ cnt,
                                                unsigned* __restrict__ bsum, int N) {
  __shared__ unsigned ws[16];
  int tid = threadIdx.x;
  int i = blockIdx.x * 1024 + tid;
  unsigned v = (i < N) ? cnt[i] : 0u;
  #pragma unroll
  for (int d = 32; d; d >>= 1) v += __shfl_xor(v, d, 64);
  if ((tid & 63) == 0) ws[tid >> 6] = v;
  __syncthreads();
  if (tid == 0) {
    unsigned s = 0;
    #pragma unroll
    for (int j = 0; j < 16; ++j) s += ws[j];
    bsum[blockIdx.x] = s;
  }
}

// pass 2: exclusive scan of <=128 block sums (single block, 2 waves)
__global__ void __launch_bounds__(128) k_scan2(const unsigned* __restrict__ bsum,
                                               unsigned* __restrict__ boff, int nb,
                                               int* __restrict__ row_ptr, int N, int E) {
  __shared__ unsigned w0tot;
  int tid = threadIdx.x, lane = tid & 63, wv = tid >> 6;
  unsigned v = (tid < nb) ? bsum[tid] : 0u;
  unsigned x = v;
  #pragma unroll
  for (int d = 1; d < 64; d <<= 1) {
    unsigned y = __shfl_up(x, (unsigned)d, 64);
    if (lane >= d) x += y;
  }
  if (wv == 0 && lane == 63) w0tot = x;
  __syncthreads();
  unsigned excl = (x - v) + (wv ? w0tot : 0u);
  if (tid < nb) boff[tid] = excl;
  if (tid == 0) row_ptr[N] = E;
}

// pass 3: per-block exclusive scan + block offset -> row_ptr, cursor
__global__ void __launch_bounds__(1024) k_scan3(const unsigned* __restrict__ cnt,
                                                const unsigned* __restrict__ boff,
                                                int* __restrict__ row_ptr,
                                                int* __restrict__ cursor, int N) {
  __shared__ unsigned ws[16];
  __shared__ unsigned wexcl[16];
  int tid = threadIdx.x, lane = tid & 63, wv = tid >> 6;
  int i = blockIdx.x * 1024 + tid;
  unsigned v = (i < N) ? cnt[i] : 0u;
  unsigned x = v;
  #pragma unroll
  for (int d = 1; d < 64; d <<= 1) {
    unsigned y = __shfl_up(x, (unsigned)d, 64);
    if (lane >= d) x += y;
  }
  if (lane == 63) ws[wv] = x;
  __syncthreads();
  if (tid == 0) {
    unsigned run = 0;
    #pragma unroll
    for (int j = 0; j < 16; ++j) { unsigned t = ws[j]; wexcl[j] = run; run += t; }
  }
  __syncthreads();
  unsigned excl = boff[blockIdx.x] + wexcl[wv] + (x - v);
  if (i < N) { row_ptr[i] = (int)excl; cursor[i] = (int)excl; }
}

// ---------------- scatter edges into CSR order, packed (src, coef) ----------------
__global__ void __launch_bounds__(256) k_scatter(const int* __restrict__ src,
                                                 const int* __restrict__ dst,
                                                 const float* __restrict__ dis,
                                                 int* __restrict__ cursor,
                                                 int2* __restrict__ edges, int E) {
  int i = blockIdx.x * 256 + threadIdx.x;
  if (i < E) {
    int s = src[i], d = dst[i];
    int pos = atomicAdd(&cursor[d], 1);
    edges[pos] = make_int2(s, __float_as_int(dis[s] * dis[d]));
  }
}

// ---------------- GEMM: H[M][FOUT] = X[M][128] @ W[128][FOUT] ----------------
template <int FOUT>
__global__ void __launch_bounds__(256) k_gemm(const float* __restrict__ X,
                                              const float* __restrict__ W,
                                              float* __restrict__ H, int M) {
  constexpr int CPT = FOUT / 16;           // cols per thread (8 or 4)
  constexpr int F4 = FOUT / 4;
  __shared__ float Xs[32][72];             // [k][m], padded stride
  __shared__ float Ws[32][FOUT];
  int tid = threadIdx.x;
  int tx = tid & 15, ty = tid >> 4;
  int m0 = blockIdx.x * 64;

  float acc[4][CPT];
  #pragma unroll
  for (int i = 0; i < 4; ++i)
    #pragma unroll
    for (int j = 0; j < CPT; ++j) acc[i][j] = 0.f;

  for (int k0 = 0; k0 < 128; k0 += 32) {
    #pragma unroll
    for (int idx = tid; idx < 512; idx += 256) {
      int r = idx >> 3, c4 = idx & 7;
      int g = m0 + r;
      float4 v = make_float4(0.f, 0.f, 0.f, 0.f);
      if (g < M) v = *reinterpret_cast<const float4*>(X + (size_t)g * 128 + k0 + c4 * 4);
      Xs[c4 * 4 + 0][r] = v.x;
      Xs[c4 * 4 + 1][r] = v.y;
      Xs[c4 * 4 + 2][r] = v.z;
      Xs[c4 * 4 + 3][r] = v.w;
    }
    for (int idx = tid; idx < 32 * F4; idx += 256) {
      int kk = idx / F4, c4 = idx % F4;
      float4 v = *reinterpret_cast<const float4*>(W + (size_t)(k0 + kk) * FOUT + c4 * 4);
      *reinterpret_cast<float4*>(&Ws[kk][c4 * 4]) = v;
    }
    __syncthreads();

    #pragma unroll
    for (int kk = 0; kk < 32; ++kk) {
      float4 xv = *reinterpret_cast<const float4*>(&Xs[kk][ty * 4]);
      float xa[4] = {xv.x, xv.y, xv.z, xv.w};
      float wl[CPT];
      float4 w0 = *reinterpret_cast<const float4*>(&Ws[kk][tx * CPT]);
      wl[0] = w0.x; wl[1] = w0.y; wl[2] = w0.z; wl[3] = w0.w;
      if (CPT == 8) {
        float4 w1 = *reinterpret_cast<const float4*>(&Ws[kk][tx * CPT + 4]);
        wl[4] = w1.x; wl[5] = w1.y; wl[6] = w1.z; wl[7] = w1.w;
      }
      #pragma unroll
      for (int i = 0; i < 4; ++i)
        #pragma unroll
        for (int j = 0; j < CPT; ++j)
          acc[i][j] = fmaf(xa[i], wl[j], acc[i][j]);
    }
    __syncthreads();
  }

  #pragma unroll
  for (int i = 0; i < 4; ++i) {
    int g = m0 + ty * 4 + i;
    if (g < M) {
      float4 o0 = make_float4(acc[i][0], acc[i][1], acc[i][2], acc[i][3]);
      *reinterpret_cast<float4*>(H + (size_t)g * FOUT + tx * CPT) = o0;
      if (CPT == 8) {
        float4 o1 = make_float4(acc[i][4], acc[i][5], acc[i][6], acc[i][7]);
        *reinterpret_cast<float4*>(H + (size_t)g * FOUT + tx * CPT + 4) = o1;
      }
    }
  }
}

// ---------------- aggregate, 8-way software-pipelined gather ----------------
// one wave per node; edges[p] = (src, coef-bits)
template <int F, bool RELU>
__global__ void __launch_bounds__(256) k_agg(const float* __restrict__ h,
                                             const int* __restrict__ row_ptr,
                                             const int2* __restrict__ edges,
                                             const float* __restrict__ dis,
                                             const float* __restrict__ bias,
                                             float* __restrict__ out, int N) {
  int n = blockIdx.x * 4 + (threadIdx.x >> 6);
  int lane = threadIdx.x & 63;
  if (n >= N) return;
  int beg = row_ptr[n], end = row_ptr[n + 1];

  if (F == 128) {
    const float2* __restrict__ h2 = reinterpret_cast<const float2*>(h);
    float2 acc = make_float2(0.f, 0.f);
    int p = beg;
    for (; p + 8 <= end; p += 8) {
      int2 e[8];
      #pragma unroll
      for (int j = 0; j < 8; ++j) e[j] = edges[p + j];
      float2 v[8];
      #pragma unroll
      for (int j = 0; j < 8; ++j) v[j] = h2[(size_t)e[j].x * 64 + lane];
      #pragma unroll
      for (int j = 0; j < 8; ++j) {
        float c = __int_as_float(e[j].y);
        acc.x = fmaf(v[j].x, c, acc.x);
        acc.y = fmaf(v[j].y, c, acc.y);
      }
    }
    if (p + 4 <= end) {
      int2 e[4];
      #pragma unroll
      for (int j = 0; j < 4; ++j) e[j] = edges[p + j];
      float2 v[4];
      #pragma unroll
      for (int j = 0; j < 4; ++j) v[j] = h2[(size_t)e[j].x * 64 + lane];
      #pragma unroll
      for (int j = 0; j < 4; ++j) {
        float c = __int_as_float(e[j].y);
        acc.x = fmaf(v[j].x, c, acc.x);
        acc.y = fmaf(v[j].y, c, acc.y);
      }
      p += 4;
    }
    for (; p < end; ++p) {
      int2 e = edges[p];
      float c = __int_as_float(e.y);
      float2 v = h2[(size_t)e.x * 64 + lane];
      acc.x = fmaf(v.x, c, acc.x);
      acc.y = fmaf(v.y, c, acc.y);
    }
    float dn = dis[n];
    float sc = dn * dn;
    float2 hv = h2[(size_t)n * 64 + lane];
    float2 b = reinterpret_cast<const float2*>(bias)[lane];
    acc.x = fmaf(sc, hv.x, acc.x) + b.x;
    acc.y = fmaf(sc, hv.y, acc.y) + b.y;
    if (RELU) { acc.x = fmaxf(acc.x, 0.f); acc.y = fmaxf(acc.y, 0.f); }
    reinterpret_cast<float2*>(out)[(size_t)n * 64 + lane] = acc;
  } else {
    float acc = 0.f;
    int p = beg;
    for (; p + 8 <= end; p += 8) {
      int2 e[8];
      #pragma unroll
      for (int j = 0; j < 8; ++j) e[j] = edges[p + j];
      float v[8];
      #pragma unroll
      for (int j = 0; j < 8; ++j) v[j] = h[(size_t)e[j].x * F + lane];
      #pragma unroll
      for (int j = 0; j < 8; ++j) acc = fmaf(v[j], __int_as_float(e[j].y), acc);
    }
    for (; p < end; ++p) {
      int2 e = edges[p];
      acc = fmaf(h[(size_t)e.x * F + lane], __int_as_float(e.y), acc);
    }
    float dn = dis[n];
    acc = fmaf(dn * dn, h[(size_t)n * F + lane], acc) + bias[lane];
    if (RELU) acc = fmaxf(acc, 0.f);
    out[(size_t)n * F + lane] = acc;
  }
}

// ---------------- log_softmax over 64 cols, one wave per node ----------------
__global__ void __launch_bounds__(256) k_lsm(const float* __restrict__ in,
                                             float* __restrict__ out, int N) {
  int n = blockIdx.x * 4 + (threadIdx.x >> 6);
  int lane = threadIdx.x & 63;
  if (n >= N) return;
  float v = in[(size_t)n * 64 + lane];
  float m = v;
  #pragma unroll
  for (int d = 32; d; d >>= 1) m = fmaxf(m, __shfl_xor(m, d, 64));
  float e = expf(v - m);
  #pragma unroll
  for (int d = 32; d; d >>= 1) e += __shfl_xor(e, d, 64);
  out[(size_t)n * 64 + lane] = v - m - logf(e);
}

extern "C" void kernel_launch(void* const* d_in, const int* in_sizes, int n_in,
                              void* d_out, int out_size, void* d_ws, size_t ws_size,
                              hipStream_t stream) {
  const float* x  = (const float*)d_in[0];
  const int*   ei = (const int*)d_in[1];
  const float* W0 = (const float*)d_in[2];
  const float* b0 = (const float*)d_in[3];
  const float* W1 = (const float*)d_in[4];
  const float* b1 = (const float*)d_in[5];
  const float* W2 = (const float*)d_in[6];
  const float* b2 = (const float*)d_in[7];
  float* out = (float*)d_out;

  const int N = NN, E = NE;
  const int* src = ei;
  const int* dst = ei + E;

  char* ws = (char*)d_ws;
  size_t off = 0;
  auto alloc = [&](size_t bytes) -> void* {
    off = (off + 255) & ~(size_t)255;
    void* p = ws + off;
    off += bytes;
    return p;
  };
  float*    dis     = (float*)alloc((size_t)N * 4);
  unsigned* cnt     = (unsigned*)alloc((size_t)N * 4);
  int*      row_ptr = (int*)alloc((size_t)(N + 1) * 4);
  int*      cursor  = (int*)alloc((size_t)N * 4);
  int2*     edges   = (int2*)alloc((size_t)E * 8);
  unsigned* bsum    = (unsigned*)alloc(128 * 4);
  unsigned* boff    = (unsigned*)alloc(128 * 4);
  float*    bufA    = (float*)alloc((size_t)N * 128 * 4);
  float*    bufB    = (float*)alloc((size_t)N * 128 * 4);

  const int nb = (N + 1023) / 1024;  // 98 scan blocks

  // ---- CSR build ----
  hipMemsetAsync(cnt, 0, (size_t)N * 4, stream);
  k_count<<<(E + 255) / 256, 256, 0, stream>>>(dst, cnt, E);
  k_dis<<<(N + 255) / 256, 256, 0, stream>>>(cnt, dis, N);
  k_scan1<<<nb, 1024, 0, stream>>>(cnt, bsum, N);
  k_scan2<<<1, 128, 0, stream>>>(bsum, boff, nb, row_ptr, N, E);
  k_scan3<<<nb, 1024, 0, stream>>>(cnt, boff, row_ptr, cursor, N);
  k_scatter<<<(E + 255) / 256, 256, 0, stream>>>(src, dst, dis, cursor, edges, E);

  const int gemm_grid = (N + 63) / 64;   // 1563
  const int node_grid = (N + 3) / 4;     // 25000

  // ---- layer 0 ----
  k_gemm<128><<<gemm_grid, 256, 0, stream>>>(x, W0, bufA, N);
  k_agg<128, true><<<node_grid, 256, 0, stream>>>(bufA, row_ptr, edges, dis, b0, bufB, N);
  // ---- layer 1 ----
  k_gemm<128><<<gemm_grid, 256, 0, stream>>>(bufB, W1, bufA, N);
  k_agg<128, true><<<node_grid, 256, 0, stream>>>(bufA, row_ptr, edges, dis, b1, bufB, N);
  // ---- layer 2 ----
  k_gemm<64><<<gemm_grid, 256, 0, stream>>>(bufB, W2, bufA, N);
  k_agg<64, false><<<node_grid, 256, 0, stream>>>(bufA, row_ptr, edges, dis, b2, bufB, N);
  // ---- log_softmax ----
  k_lsm<<<node_grid, 256, 0, stream>>>(bufB, out, N);
}

// Round 3
// 617.880 us; speedup vs baseline: 1.6165x; 1.1491x over previous
//
#include <hip/hip_runtime.h>
#include <cstddef>

#define NN 100000
#define NE 1600000

typedef unsigned int uint;
typedef unsigned short ushort;

__device__ inline uint bf16_rne(float f) {          // fp32 -> bf16 bits (round-nearest-even)
  uint u = __float_as_uint(f);
  u += 0x7fffu + ((u >> 16) & 1u);
  return u >> 16;
}

// ---------------- degree count ----------------
__global__ void __launch_bounds__(256) k_count(const int* __restrict__ dst,
                                               unsigned* __restrict__ cnt, int E) {
  int i = blockIdx.x * 256 + threadIdx.x;
  if (i < E) atomicAdd(&cnt[dst[i]], 1u);
}

__global__ void __launch_bounds__(256) k_dis(const unsigned* __restrict__ cnt,
                                             float* __restrict__ dis, int N) {
  int i = blockIdx.x * 256 + threadIdx.x;
  if (i < N) dis[i] = rsqrtf((float)cnt[i] + 1.0f);
}

// ---------------- 3-pass scan ----------------
__global__ void __launch_bounds__(1024) k_scan1(const unsigned* __restrict__ cnt,
                                                unsigned* __restrict__ bsum, int N) {
  __shared__ unsigned ws[16];
  int tid = threadIdx.x;
  int i = blockIdx.x * 1024 + tid;
  unsigned v = (i < N) ? cnt[i] : 0u;
  #pragma unroll
  for (int d = 32; d; d >>= 1) v += __shfl_xor(v, d, 64);
  if ((tid & 63) == 0) ws[tid >> 6] = v;
  __syncthreads();
  if (tid == 0) {
    unsigned s = 0;
    #pragma unroll
    for (int j = 0; j < 16; ++j) s += ws[j];
    bsum[blockIdx.x] = s;
  }
}

__global__ void __launch_bounds__(128) k_scan2(const unsigned* __restrict__ bsum,
                                               unsigned* __restrict__ boff, int nb,
                                               int* __restrict__ row_ptr, int N, int E) {
  __shared__ unsigned w0tot;
  int tid = threadIdx.x, lane = tid & 63, wv = tid >> 6;
  unsigned v = (tid < nb) ? bsum[tid] : 0u;
  unsigned x = v;
  #pragma unroll
  for (int d = 1; d < 64; d <<= 1) {
    unsigned y = __shfl_up(x, (unsigned)d, 64);
    if (lane >= d) x += y;
  }
  if (wv == 0 && lane == 63) w0tot = x;
  __syncthreads();
  unsigned excl = (x - v) + (wv ? w0tot : 0u);
  if (tid < nb) boff[tid] = excl;
  if (tid == 0) row_ptr[N] = E;
}

__global__ void __launch_bounds__(1024) k_scan3(const unsigned* __restrict__ cnt,
                                                const unsigned* __restrict__ boff,
                                                int* __restrict__ row_ptr,
                                                int* __restrict__ cursor, int N) {
  __shared__ unsigned ws[16];
  __shared__ unsigned wexcl[16];
  int tid = threadIdx.x, lane = tid & 63, wv = tid >> 6;
  int i = blockIdx.x * 1024 + tid;
  unsigned v = (i < N) ? cnt[i] : 0u;
  unsigned x = v;
  #pragma unroll
  for (int d = 1; d < 64; d <<= 1) {
    unsigned y = __shfl_up(x, (unsigned)d, 64);
    if (lane >= d) x += y;
  }
  if (lane == 63) ws[wv] = x;
  __syncthreads();
  if (tid == 0) {
    unsigned run = 0;
    #pragma unroll
    for (int j = 0; j < 16; ++j) { unsigned t = ws[j]; wexcl[j] = run; run += t; }
  }
  __syncthreads();
  unsigned excl = boff[blockIdx.x] + wexcl[wv] + (x - v);
  if (i < N) { row_ptr[i] = (int)excl; cursor[i] = (int)excl; }
}

// ---------------- scatter edges into CSR order, packed (src, coef) ----------------
__global__ void __launch_bounds__(256) k_scatter(const int* __restrict__ src,
                                                 const int* __restrict__ dst,
                                                 const float* __restrict__ dis,
                                                 int* __restrict__ cursor,
                                                 int2* __restrict__ edges, int E) {
  int i = blockIdx.x * 256 + threadIdx.x;
  if (i < E) {
    int s = src[i], d = dst[i];
    int pos = atomicAdd(&cursor[d], 1);
    edges[pos] = make_int2(s, __float_as_int(dis[s] * dis[d]));
  }
}

// ---------------- GEMM: H[M][FOUT] = X[M][128] @ W[128][FOUT], plus bf16 copy ----------------
template <int FOUT>
__global__ void __launch_bounds__(256) k_gemm(const float* __restrict__ X,
                                              const float* __restrict__ W,
                                              float* __restrict__ H,
                                              uint* __restrict__ Hb,   // bf16-packed copy (2 elems/uint)
                                              int M) {
  constexpr int CPT = FOUT / 16;           // cols per thread (8 or 4)
  constexpr int F4 = FOUT / 4;
  __shared__ float Xs[32][72];
  __shared__ float Ws[32][FOUT];
  int tid = threadIdx.x;
  int tx = tid & 15, ty = tid >> 4;
  int m0 = blockIdx.x * 64;

  float acc[4][CPT];
  #pragma unroll
  for (int i = 0; i < 4; ++i)
    #pragma unroll
    for (int j = 0; j < CPT; ++j) acc[i][j] = 0.f;

  for (int k0 = 0; k0 < 128; k0 += 32) {
    #pragma unroll
    for (int idx = tid; idx < 512; idx += 256) {
      int r = idx >> 3, c4 = idx & 7;
      int g = m0 + r;
      float4 v = make_float4(0.f, 0.f, 0.f, 0.f);
      if (g < M) v = *reinterpret_cast<const float4*>(X + (size_t)g * 128 + k0 + c4 * 4);
      Xs[c4 * 4 + 0][r] = v.x;
      Xs[c4 * 4 + 1][r] = v.y;
      Xs[c4 * 4 + 2][r] = v.z;
      Xs[c4 * 4 + 3][r] = v.w;
    }
    for (int idx = tid; idx < 32 * F4; idx += 256) {
      int kk = idx / F4, c4 = idx % F4;
      float4 v = *reinterpret_cast<const float4*>(W + (size_t)(k0 + kk) * FOUT + c4 * 4);
      *reinterpret_cast<float4*>(&Ws[kk][c4 * 4]) = v;
    }
    __syncthreads();

    #pragma unroll
    for (int kk = 0; kk < 32; ++kk) {
      float4 xv = *reinterpret_cast<const float4*>(&Xs[kk][ty * 4]);
      float xa[4] = {xv.x, xv.y, xv.z, xv.w};
      float wl[CPT];
      float4 w0 = *reinterpret_cast<const float4*>(&Ws[kk][tx * CPT]);
      wl[0] = w0.x; wl[1] = w0.y; wl[2] = w0.z; wl[3] = w0.w;
      if (CPT == 8) {
        float4 w1 = *reinterpret_cast<const float4*>(&Ws[kk][tx * CPT + 4]);
        wl[4] = w1.x; wl[5] = w1.y; wl[6] = w1.z; wl[7] = w1.w;
      }
      #pragma unroll
      for (int i = 0; i < 4; ++i)
        #pragma unroll
        for (int j = 0; j < CPT; ++j)
          acc[i][j] = fmaf(xa[i], wl[j], acc[i][j]);
    }
    __syncthreads();
  }

  #pragma unroll
  for (int i = 0; i < 4; ++i) {
    int g = m0 + ty * 4 + i;
    if (g < M) {
      float4 o0 = make_float4(acc[i][0], acc[i][1], acc[i][2], acc[i][3]);
      *reinterpret_cast<float4*>(H + (size_t)g * FOUT + tx * CPT) = o0;
      if (CPT == 8) {
        float4 o1 = make_float4(acc[i][4], acc[i][5], acc[i][6], acc[i][7]);
        *reinterpret_cast<float4*>(H + (size_t)g * FOUT + tx * CPT + 4) = o1;
        uint4 pb;
        pb.x = bf16_rne(acc[i][0]) | (bf16_rne(acc[i][1]) << 16);
        pb.y = bf16_rne(acc[i][2]) | (bf16_rne(acc[i][3]) << 16);
        pb.z = bf16_rne(acc[i][4]) | (bf16_rne(acc[i][5]) << 16);
        pb.w = bf16_rne(acc[i][6]) | (bf16_rne(acc[i][7]) << 16);
        *reinterpret_cast<uint4*>(Hb + (size_t)g * (FOUT / 2) + tx * 4) = pb;
      } else {
        uint2 pb;
        pb.x = bf16_rne(acc[i][0]) | (bf16_rne(acc[i][1]) << 16);
        pb.y = bf16_rne(acc[i][2]) | (bf16_rne(acc[i][3]) << 16);
        *reinterpret_cast<uint2*>(Hb + (size_t)g * (FOUT / 2) + tx * 2) = pb;
      }
    }
  }
}

// ---------------- aggregate: bf16 neighbor gather, fp32 self-loop/accum ----------------
// one wave per node; edges[p] = (src, coef-bits)
template <int F, bool RELU, bool LSM>
__global__ void __launch_bounds__(256) k_agg(const float* __restrict__ h,
                                             const uint* __restrict__ hb,   // bf16-packed
                                             const int* __restrict__ row_ptr,
                                             const int2* __restrict__ edges,
                                             const float* __restrict__ dis,
                                             const float* __restrict__ bias,
                                             float* __restrict__ out, int N) {
  int n = blockIdx.x * 4 + (threadIdx.x >> 6);
  int lane = threadIdx.x & 63;
  if (n >= N) return;
  int beg = row_ptr[n], end = row_ptr[n + 1];

  if (F == 128) {
    // lane owns elements {2*lane, 2*lane+1}: one packed uint per edge row
    float2 acc = make_float2(0.f, 0.f);
    int p = beg;
    for (; p + 8 <= end; p += 8) {
      int2 e[8];
      #pragma unroll
      for (int j = 0; j < 8; ++j) e[j] = edges[p + j];
      uint v[8];
      #pragma unroll
      for (int j = 0; j < 8; ++j) v[j] = hb[(size_t)e[j].x * 64 + lane];
      #pragma unroll
      for (int j = 0; j < 8; ++j) {
        float c = __int_as_float(e[j].y);
        acc.x = fmaf(__uint_as_float(v[j] << 16), c, acc.x);
        acc.y = fmaf(__uint_as_float(v[j] & 0xffff0000u), c, acc.y);
      }
    }
    if (p + 4 <= end) {
      int2 e[4];
      #pragma unroll
      for (int j = 0; j < 4; ++j) e[j] = edges[p + j];
      uint v[4];
      #pragma unroll
      for (int j = 0; j < 4; ++j) v[j] = hb[(size_t)e[j].x * 64 + lane];
      #pragma unroll
      for (int j = 0; j < 4; ++j) {
        float c = __int_as_float(e[j].y);
        acc.x = fmaf(__uint_as_float(v[j] << 16), c, acc.x);
        acc.y = fmaf(__uint_as_float(v[j] & 0xffff0000u), c, acc.y);
      }
      p += 4;
    }
    for (; p < end; ++p) {
      int2 e = edges[p];
      float c = __int_as_float(e.y);
      uint v = hb[(size_t)e.x * 64 + lane];
      acc.x = fmaf(__uint_as_float(v << 16), c, acc.x);
      acc.y = fmaf(__uint_as_float(v & 0xffff0000u), c, acc.y);
    }
    const float2* __restrict__ h2 = reinterpret_cast<const float2*>(h);
    float dn = dis[n];
    float sc = dn * dn;
    float2 hv = h2[(size_t)n * 64 + lane];
    float2 b = reinterpret_cast<const float2*>(bias)[lane];
    acc.x = fmaf(sc, hv.x, acc.x) + b.x;
    acc.y = fmaf(sc, hv.y, acc.y) + b.y;
    if (RELU) { acc.x = fmaxf(acc.x, 0.f); acc.y = fmaxf(acc.y, 0.f); }
    reinterpret_cast<float2*>(out)[(size_t)n * 64 + lane] = acc;
  } else {
    // F == 64: lane owns 1 element; bf16 row = 128 B, one ushort per lane
    const ushort* __restrict__ hbs = reinterpret_cast<const ushort*>(hb);
    float acc = 0.f;
    int p = beg;
    for (; p + 8 <= end; p += 8) {
      int2 e[8];
      #pragma unroll
      for (int j = 0; j < 8; ++j) e[j] = edges[p + j];
      ushort v[8];
      #pragma unroll
      for (int j = 0; j < 8; ++j) v[j] = hbs[(size_t)e[j].x * 64 + lane];
      #pragma unroll
      for (int j = 0; j < 8; ++j)
        acc = fmaf(__uint_as_float((uint)v[j] << 16), __int_as_float(e[j].y), acc);
    }
    for (; p < end; ++p) {
      int2 e = edges[p];
      ushort v = hbs[(size_t)e.x * 64 + lane];
      acc = fmaf(__uint_as_float((uint)v << 16), __int_as_float(e.y), acc);
    }
    float dn = dis[n];
    acc = fmaf(dn * dn, h[(size_t)n * 64 + lane], acc) + bias[lane];
    if (RELU) acc = fmaxf(acc, 0.f);
    if (LSM) {
      float m = acc;
      #pragma unroll
      for (int d = 32; d; d >>= 1) m = fmaxf(m, __shfl_xor(m, d, 64));
      float e = expf(acc - m);
      #pragma unroll
      for (int d = 32; d; d >>= 1) e += __shfl_xor(e, d, 64);
      acc = acc - m - logf(e);
    }
    out[(size_t)n * 64 + lane] = acc;
  }
}

extern "C" void kernel_launch(void* const* d_in, const int* in_sizes, int n_in,
                              void* d_out, int out_size, void* d_ws, size_t ws_size,
                              hipStream_t stream) {
  const float* x  = (const float*)d_in[0];
  const int*   ei = (const int*)d_in[1];
  const float* W0 = (const float*)d_in[2];
  const float* b0 = (const float*)d_in[3];
  const float* W1 = (const float*)d_in[4];
  const float* b1 = (const float*)d_in[5];
  const float* W2 = (const float*)d_in[6];
  const float* b2 = (const float*)d_in[7];
  float* out = (float*)d_out;

  const int N = NN, E = NE;
  const int* src = ei;
  const int* dst = ei + E;

  char* ws = (char*)d_ws;
  size_t off = 0;
  auto alloc = [&](size_t bytes) -> void* {
    off = (off + 255) & ~(size_t)255;
    void* p = ws + off;
    off += bytes;
    return p;
  };
  float*    dis     = (float*)alloc((size_t)N * 4);
  unsigned* cnt     = (unsigned*)alloc((size_t)N * 4);
  int*      row_ptr = (int*)alloc((size_t)(N + 1) * 4);
  int*      cursor  = (int*)alloc((size_t)N * 4);
  int2*     edges   = (int2*)alloc((size_t)E * 8);
  unsigned* bsum    = (unsigned*)alloc(128 * 4);
  unsigned* boff    = (unsigned*)alloc(128 * 4);
  float*    bufA    = (float*)alloc((size_t)N * 128 * 4);   // gemm fp32 out
  uint*     bufAb   = (uint*)alloc((size_t)N * 128 * 2);    // gemm bf16 out (packed)
  float*    bufB    = (float*)alloc((size_t)N * 128 * 4);   // agg out / gemm in

  const int nb = (N + 1023) / 1024;

  // ---- CSR build ----
  hipMemsetAsync(cnt, 0, (size_t)N * 4, stream);
  k_count<<<(E + 255) / 256, 256, 0, stream>>>(dst, cnt, E);
  k_dis<<<(N + 255) / 256, 256, 0, stream>>>(cnt, dis, N);
  k_scan1<<<nb, 1024, 0, stream>>>(cnt, bsum, N);
  k_scan2<<<1, 128, 0, stream>>>(bsum, boff, nb, row_ptr, N, E);
  k_scan3<<<nb, 1024, 0, stream>>>(cnt, boff, row_ptr, cursor, N);
  k_scatter<<<(E + 255) / 256, 256, 0, stream>>>(src, dst, dis, cursor, edges, E);

  const int gemm_grid = (N + 63) / 64;   // 1563
  const int node_grid = (N + 3) / 4;     // 25000

  // ---- layer 0 ----
  k_gemm<128><<<gemm_grid, 256, 0, stream>>>(x, W0, bufA, bufAb, N);
  k_agg<128, true, false><<<node_grid, 256, 0, stream>>>(bufA, bufAb, row_ptr, edges, dis, b0, bufB, N);
  // ---- layer 1 ----
  k_gemm<128><<<gemm_grid, 256, 0, stream>>>(bufB, W1, bufA, bufAb, N);
  k_agg<128, true, false><<<node_grid, 256, 0, stream>>>(bufA, bufAb, row_ptr, edges, dis, b1, bufB, N);
  // ---- layer 2 (fused log_softmax epilogue) ----
  k_gemm<64><<<gemm_grid, 256, 0, stream>>>(bufB, W2, bufA, bufAb, N);
  k_agg<64, false, true><<<node_grid, 256, 0, stream>>>(bufA, bufAb, row_ptr, edges, dis, b2, out, N);
}